// Round 6
// baseline (1976.417 us; speedup 1.0000x reference)
//
#include <hip/hip_runtime.h>

#define NROWS 65536
#define KC    1024
#define DD    256
#define ND    (NROWS*DD)      /* 16777216 */
#define KD    (KC*DD)         /* 262144 */
#define ROWS  32              /* rows per block */
#define CAP   16              /* candidate list capacity per row */
#define MARGIN 0.0625f        /* >12x the FMA-vs-mul/add screen error bound */

/* output offsets (floats), concatenated in reference return order */
#define O_ZQ   0
#define O_DIST ND
#define O_IDX  (ND+1)
#define O_EMB  (ND+1+NROWS)
#define O_MT   (O_EMB+KD)
#define O_NT   (O_MT+KD)

/* ===== exact-replica arithmetic contract (validated round 5) =====
   ref dist d2[r][c] = fadd( fsub( zsq[r], fmul(2, dot) ), wsq[c] )
   dot  = sequential ascending-k, SEPARATE mul+add roundings, single acc
   zsq/wsq = strict sequential sum of squares (mul+add, ascending)
   argmin  = first occurrence of min. */

static __device__ __forceinline__ void minmerge(float& bv, int& bi, float ov, int oi){
  if (ov < bv || (ov == bv && oi < bi)) { bv = ov; bi = oi; }
}

static __device__ __forceinline__ float seq_sumsq_256(const float* __restrict__ x){
  float s = __fmul_rn(x[0], x[0]);
  for (int i=1;i<256;i++) s = __fadd_rn(s, __fmul_rn(x[i], x[i]));
  return s;
}

__global__ __launch_bounds__(256,1) void vq_wsq_kernel(const float* __restrict__ W,
                                                       float* __restrict__ wsq){
  const int k = blockIdx.x*256 + threadIdx.x;
  wsq[k] = seq_sumsq_256(W + (size_t)k*DD);
}

/* 32 rows/block, 2048 blocks. 256 thr = 8 row-groups (GRp, 4 rows each)
   x 32 code-lanes (TX, 8 codes each). W read direct from global (L1/L2-hot),
   z from LDS (broadcast), no inner barriers -> 4 blocks/CU. */
__global__ __launch_bounds__(256,4) void vq_main_kernel(
    const float* __restrict__ ze, const float* __restrict__ W,
    const float* __restrict__ wsq,
    float* __restrict__ out, float* __restrict__ st, float* __restrict__ nt,
    float* __restrict__ dist_acc)
{
  __shared__ float zeS[ROWS*256];     /* 32 KB */
  __shared__ float wsqS[KC];          /* 4 KB, all 1024 */
  __shared__ float zsqS[ROWS];
  __shared__ int   cntS[ROWS];
  __shared__ int   listS[ROWS][CAP];
  __shared__ int   riS[ROWS];

  const int tid = threadIdx.x;
  const int blk = blockIdx.x;
  const int GRp = tid >> 5;   /* 0..7 */
  const int TX  = tid & 31;   /* 0..31 */

  /* stage ze tile + wsq + init counters */
  {
    const float* zb = ze + (size_t)blk*ROWS*DD;
    #pragma unroll
    for (int i=0;i<8;i++){
      int f = i*256 + tid;
      *(float4*)&zeS[f*4] = *(const float4*)&zb[(size_t)f*4];
    }
    #pragma unroll
    for (int i=0;i<4;i++) wsqS[i*256 + tid] = wsq[i*256 + tid];
    if (tid < ROWS) cntS[tid] = 0;
  }
  __syncthreads();
  if (tid < ROWS) zsqS[tid] = seq_sumsq_256(&zeS[tid*256]);
  __syncthreads();

  float rv[4]; int ri[4];
  #pragma unroll
  for (int e=0;e<4;e++){ rv[e]=3.4e38f; ri[e]=0x7fffffff; }

  for (int nc=0; nc<4; nc++){
    float acc[32];
    #pragma unroll
    for (int a=0;a<32;a++) acc[a]=0.f;

    /* per-thread code rows: ca_m = nc*256 + 4*TX + m, cb_m = ca_m + 128 */
    const float* pa = W + (size_t)(nc*256 + 4*TX)*DD;
    const float* pb = pa + (size_t)128*DD;

    #pragma unroll 2
    for (int dg=0; dg<64; ++dg){
      const int d0 = dg*4;
      float4 wa[4], wb[4];
      #pragma unroll
      for (int m=0;m<4;m++){
        wa[m] = *(const float4*)(pa + (size_t)m*DD + d0);
        wb[m] = *(const float4*)(pb + (size_t)m*DD + d0);
      }
      float4 z4[4];
      #pragma unroll
      for (int e=0;e<4;e++)
        z4[e] = *(const float4*)&zeS[(4*GRp+e)*256 + d0];
      #pragma unroll
      for (int d2=0; d2<4; d2++){
        #pragma unroll
        for (int e=0;e<4;e++){
          const float zv = (d2==0)?z4[e].x:(d2==1)?z4[e].y:(d2==2)?z4[e].z:z4[e].w;
          #pragma unroll
          for (int m=0;m<4;m++){
            const float wav = (d2==0)?wa[m].x:(d2==1)?wa[m].y:(d2==2)?wa[m].z:wa[m].w;
            const float wbv = (d2==0)?wb[m].x:(d2==1)?wb[m].y:(d2==2)?wb[m].z:wb[m].w;
            acc[e*8+m]   = __builtin_fmaf(zv, wav, acc[e*8+m]);
            acc[e*8+4+m] = __builtin_fmaf(zv, wbv, acc[e*8+4+m]);
          }
        }
      }
    }

    /* chunk argmin (screen) + candidate collection */
    #pragma unroll
    for (int e=0;e<4;e++){
      const int row = 4*GRp + e;
      const float zs = zsqS[row];
      float cb = 3.4e38f; int ci = 0x7fffffff;
      #pragma unroll
      for (int j=0;j<2;j++){
        #pragma unroll
        for (int m=0;m<4;m++){
          const int cl = 128*j + 4*TX + m;
          const float v = __fadd_rn(__fsub_rn(zs, __fmul_rn(2.0f, acc[e*8+j*4+m])),
                                    wsqS[nc*256 + cl]);
          minmerge(cb, ci, v, nc*256 + cl);
        }
      }
      #pragma unroll
      for (int s=1; s<32; s<<=1){
        float ov = __shfl_xor(cb, s);
        int   oi = __shfl_xor(ci, s);
        minmerge(cb, ci, ov, oi);
      }
      /* threshold uses min(running, chunk) -> guaranteed superset of
         all codes within MARGIN of the final screen min */
      const float thr = fminf(rv[e], cb) + MARGIN;
      #pragma unroll
      for (int j=0;j<2;j++){
        #pragma unroll
        for (int m=0;m<4;m++){
          const int cl = 128*j + 4*TX + m;
          const float v = __fadd_rn(__fsub_rn(zs, __fmul_rn(2.0f, acc[e*8+j*4+m])),
                                    wsqS[nc*256 + cl]);
          if (v <= thr){
            int slot = atomicAdd(&cntS[row], 1);
            if (slot < CAP) listS[row][slot] = nc*256 + cl;
          }
        }
      }
      minmerge(rv[e], ri[e], cb, ci);
    }
  }

  /* publish screen decision */
  if (TX == 0){
    #pragma unroll
    for (int e=0;e<4;e++) riS[4*GRp+e] = ri[e];
  }
  __syncthreads();

  /* exact-replica rescore for rows with >1 candidate (rare) */
  if (tid < ROWS){
    int c = cntS[tid];
    if (c > 1){
      if (c > CAP) c = CAP;
      const float zs = zsqS[tid];
      float bv = 3.4e38f; int bi = 0x7fffffff;
      for (int i=0;i<c;i++){
        const int idx = listS[tid][i];
        const float* wr = W + (size_t)idx*DD;
        const float* zr = &zeS[tid*256];
        float s = 0.f;
        for (int k=0;k<256;k++) s = __fadd_rn(s, __fmul_rn(zr[k], wr[k]));
        const float v = __fadd_rn(__fsub_rn(zs, __fmul_rn(2.0f, s)), wsqS[idx]);
        minmerge(bv, bi, v, idx);
      }
      riS[tid] = bi;
    }
  }
  __syncthreads();

  /* epilogue: per row write zq_st, idx; accumulate dist, st, nt */
  float distp = 0.f;
  #pragma unroll
  for (int e=0;e<4;e++){
    const int r    = 4*GRp + e;
    const int grow = blk*ROWS + r;
    const int gi   = riS[r];
    const float* wrow = W + (size_t)gi*DD;
    #pragma unroll
    for (int j=0;j<2;j++){
      const int d = 128*j + 4*TX;
      float4 w4 = *(const float4*)(wrow + d);
      float4 z4 = *(const float4*)&zeS[r*256 + d];
      float4 o;
      o.x = z4.x + (w4.x - z4.x);
      o.y = z4.y + (w4.y - z4.y);
      o.z = z4.z + (w4.z - z4.z);
      o.w = z4.w + (w4.w - z4.w);
      *(float4*)&out[(size_t)grow*DD + d] = o;
      float dx;
      dx = w4.x - z4.x; distp += dx*dx;
      dx = w4.y - z4.y; distp += dx*dx;
      dx = w4.z - z4.z; distp += dx*dx;
      dx = w4.w - z4.w; distp += dx*dx;
      atomicAdd(&st[(size_t)gi*DD + d + 0], z4.x);
      atomicAdd(&st[(size_t)gi*DD + d + 1], z4.y);
      atomicAdd(&st[(size_t)gi*DD + d + 2], z4.z);
      atomicAdd(&st[(size_t)gi*DD + d + 3], z4.w);
    }
    if (TX == 0){
      out[O_IDX + grow] = (float)gi;
      atomicAdd(&nt[gi], 1.0f);
    }
  }
  #pragma unroll
  for (int s=1; s<64; s<<=1) distp += __shfl_xor(distp, s);
  if ((tid & 63) == 0) atomicAdd(dist_acc, distp);
}

__global__ __launch_bounds__(256,1) void vq_tail_kernel(
    const float* __restrict__ mt, const float* __restrict__ Nt,
    const float* __restrict__ st, const float* __restrict__ nt,
    const float* __restrict__ dist_acc, float* __restrict__ out)
{
  const float G   = 0.99f;
  const float OMG = (float)(1.0 - 0.99);
  const int i = blockIdx.x*256 + threadIdx.x;
  const int k = i >> 8;
  const float ntn = __fadd_rn(__fmul_rn(G, Nt[k]), __fmul_rn(OMG, nt[k]));
  const float mtn = __fadd_rn(__fmul_rn(G, mt[i]), __fmul_rn(OMG, st[i]));
  out[O_MT  + i] = mtn;
  out[O_EMB + i] = mtn / ntn;
  if (i < KC) out[O_NT + i] = __fadd_rn(__fmul_rn(G, Nt[i]), __fmul_rn(OMG, nt[i]));
  if (i == 0) out[O_DIST] = dist_acc[0] * (1.0f/16777216.0f);
}

extern "C" void kernel_launch(void* const* d_in, const int* in_sizes, int n_in,
                              void* d_out, int out_size, void* d_ws, size_t ws_size,
                              hipStream_t stream){
  const float* ze = (const float*)d_in[0];
  const float* W  = (const float*)d_in[1];
  const float* mt = (const float*)d_in[2];
  const float* Nt = (const float*)d_in[3];
  float* out  = (float*)d_out;
  float* ws   = (float*)d_ws;
  float* st   = ws;                 /* KD  */
  float* nt   = ws + KD;            /* KC  */
  float* dist = ws + KD + KC;       /* 1   */
  float* wsq  = ws + KD + KC + 1;   /* KC  */

  hipMemsetAsync(d_ws, 0, (size_t)(KD + KC + 1)*sizeof(float), stream);
  vq_wsq_kernel <<<KC/256,     256, 0, stream>>>(W, wsq);
  vq_main_kernel<<<NROWS/ROWS, 256, 0, stream>>>(ze, W, wsq, out, st, nt, dist);
  vq_tail_kernel<<<KD/256,     256, 0, stream>>>(mt, Nt, st, nt, dist, out);
}

// Round 7
// 895.679 us; speedup vs baseline: 2.2066x; 2.2066x over previous
//
#include <hip/hip_runtime.h>

#define NROWS 65536
#define KC    1024
#define DD    256
#define ND    (NROWS*DD)      /* 16777216 */
#define KD    (KC*DD)         /* 262144 */
#define ROWS  64              /* rows per block */
#define CAP   12              /* candidate list capacity per row */
#define MARGIN 0.0625f        /* >12x the FMA-vs-mul/add screen error bound */

/* output offsets (floats), concatenated in reference return order */
#define O_ZQ   0
#define O_DIST ND
#define O_IDX  (ND+1)
#define O_EMB  (ND+1+NROWS)
#define O_MT   (O_EMB+KD)
#define O_NT   (O_MT+KD)

/* ===== exact-replica arithmetic contract (validated rounds 5/6) =====
   ref dist d2[r][c] = fadd( fsub( zsq[r], fmul(2, dot) ), wsq[c] )
   dot  = sequential ascending-k, SEPARATE mul+add roundings, single acc
   zsq/wsq = strict sequential sum of squares (mul+add, ascending)
   argmin  = first occurrence of min.
   Screen may use FMA; all candidates within MARGIN are rescored with the
   exact replica chain (superset proof: running-min monotonicity). */

static __device__ __forceinline__ void minmerge(float& bv, int& bi, float ov, int oi){
  if (ov < bv || (ov == bv && oi < bi)) { bv = ov; bi = oi; }
}

static __device__ __forceinline__ float seq_sumsq_256(const float* __restrict__ x){
  float s = __fmul_rn(x[0], x[0]);
  for (int i=1;i<256;i++) s = __fadd_rn(s, __fmul_rn(x[i], x[i]));
  return s;
}

__global__ __launch_bounds__(256,1) void vq_wsq_kernel(const float* __restrict__ W,
                                                       float* __restrict__ wsq){
  const int k = blockIdx.x*256 + threadIdx.x;
  wsq[k] = seq_sumsq_256(W + (size_t)k*DD);
}

/* W [1024][256] -> W^T [256][1024] so main-kernel staging is coalesced */
__global__ __launch_bounds__(256,1) void vq_wt_kernel(const float* __restrict__ W,
                                                      float* __restrict__ wt){
  __shared__ float t[64][65];
  const int c0 = blockIdx.x*64, d0 = blockIdx.y*64;
  const int lx = threadIdx.x & 63, ly = threadIdx.x >> 6;
  for (int r = ly; r < 64; r += 4)
    t[r][lx] = W[(size_t)(c0+r)*DD + d0 + lx];
  __syncthreads();
  for (int r = ly; r < 64; r += 4)
    wt[(size_t)(d0+r)*KC + c0 + lx] = t[lx][r];
}

/* 64 rows/block, 1024 blocks, 2 blocks/CU. 256 thr = 8 row-groups (GRp,
   8 rows each) x 32 code-lanes (TX, 8 codes each). W staged in LDS from W^T
   (coalesced float4, linear stores); z from LDS (broadcast reads). */
__global__ __launch_bounds__(256,2) void vq_main_kernel(
    const float* __restrict__ ze, const float* __restrict__ W,
    const float* __restrict__ wt, const float* __restrict__ wsq,
    float* __restrict__ out, float* __restrict__ st, float* __restrict__ nt,
    float* __restrict__ dist_acc)
{
  __shared__ float zeS[ROWS*256];     /* 64 KB */
  __shared__ float wS[8*260];         /* 8.125 KB: 8 d-slices x 256 codes (pad 260) */
  __shared__ float wsqS[256];
  __shared__ float zsqS[ROWS];
  __shared__ int   cntS[ROWS];
  __shared__ int   listS[ROWS][CAP];
  __shared__ int   riS[ROWS];
  __shared__ float rsV[4][ROWS];
  __shared__ int   rsI[4][ROWS];
  /* total ~80.7 KB -> 2 blocks/CU */

  const int tid = threadIdx.x;
  const int blk = blockIdx.x;
  const int GRp = tid >> 5;   /* 0..7 */
  const int TX  = tid & 31;   /* 0..31 */

  /* stage ze tile (coalesced float4) */
  {
    const float* zb = ze + (size_t)blk*ROWS*DD;
    #pragma unroll
    for (int i=0;i<16;i++){
      int f = i*256 + tid;
      *(float4*)&zeS[f*4] = *(const float4*)&zb[(size_t)f*4];
    }
  }
  if (tid < ROWS){
    cntS[tid] = 0;
    /* z_sq exact replica, from global (avoids 64-way LDS conflicts) */
    zsqS[tid] = seq_sumsq_256(ze + (size_t)(blk*ROWS + tid)*DD);
  }

  float rv[8]; int ri[8];
  #pragma unroll
  for (int e=0;e<8;e++){ rv[e]=3.4e38f; ri[e]=0x7fffffff; }

  /* prefetch stage 0 from W^T: tile [8 d][256 c], 2 float4/thread */
  float4 wreg[2];
  wreg[0] = *(const float4*)&wt[(size_t)(tid>>6)*KC + (tid&63)*4];
  wreg[1] = *(const float4*)&wt[(size_t)(4 + (tid>>6))*KC + (tid&63)*4];

  for (int nc=0; nc<4; nc++){
    wsqS[tid] = wsq[nc*256 + tid];   /* guarded by end-of-nc barrier */

    float acc[64];
    #pragma unroll
    for (int a=0;a<64;a++) acc[a]=0.f;

    for (int dc=0; dc<32; dc++){
      __syncthreads();
      /* store prefetched tile, row-linear float4 (conflict-free) */
      *(float4*)&wS[(tid>>6)*260 + (tid&63)*4]     = wreg[0];
      *(float4*)&wS[(4+(tid>>6))*260 + (tid&63)*4] = wreg[1];
      __syncthreads();
      /* prefetch next stage (hidden under the FMA block) */
      const int s = nc*32 + dc + 1;
      if (s < 128){
        const int ch = s>>5, db = (s&31)*8;
        wreg[0] = *(const float4*)&wt[(size_t)(db + (tid>>6))*KC + ch*256 + (tid&63)*4];
        wreg[1] = *(const float4*)&wt[(size_t)(db + 4 + (tid>>6))*KC + ch*256 + (tid&63)*4];
      }
      const int dbase = dc*8;
      #pragma unroll
      for (int dd=0; dd<8; dd+=4){
        float4 z4[8];
        #pragma unroll
        for (int e=0;e<8;e++)
          z4[e] = *(const float4*)&zeS[(8*GRp+e)*256 + dbase + dd];
        #pragma unroll
        for (int d2=0; d2<4; d2++){
          float4 wa = *(const float4*)&wS[(dd+d2)*260 + 4*TX];
          float4 wb = *(const float4*)&wS[(dd+d2)*260 + 128 + 4*TX];
          #pragma unroll
          for (int e=0;e<8;e++){
            const float zv = (d2==0)?z4[e].x:(d2==1)?z4[e].y:(d2==2)?z4[e].z:z4[e].w;
            acc[e*8+0] = __builtin_fmaf(zv, wa.x, acc[e*8+0]);
            acc[e*8+1] = __builtin_fmaf(zv, wa.y, acc[e*8+1]);
            acc[e*8+2] = __builtin_fmaf(zv, wa.z, acc[e*8+2]);
            acc[e*8+3] = __builtin_fmaf(zv, wa.w, acc[e*8+3]);
            acc[e*8+4] = __builtin_fmaf(zv, wb.x, acc[e*8+4]);
            acc[e*8+5] = __builtin_fmaf(zv, wb.y, acc[e*8+5]);
            acc[e*8+6] = __builtin_fmaf(zv, wb.z, acc[e*8+6]);
            acc[e*8+7] = __builtin_fmaf(zv, wb.w, acc[e*8+7]);
          }
        }
      }
    }

    /* screen argmin + candidate collection (FMA values) */
    #pragma unroll
    for (int e=0;e<8;e++){
      const int row = 8*GRp + e;
      const float zs = zsqS[row];
      float cb = 3.4e38f; int ci = 0x7fffffff;
      #pragma unroll
      for (int j=0;j<2;j++){
        #pragma unroll
        for (int m=0;m<4;m++){
          const int cl = 128*j + 4*TX + m;
          const float v = __fadd_rn(__fsub_rn(zs, __fmul_rn(2.0f, acc[e*8+j*4+m])),
                                    wsqS[cl]);
          minmerge(cb, ci, v, nc*256 + cl);
        }
      }
      #pragma unroll
      for (int sft=1; sft<32; sft<<=1){
        float ov = __shfl_xor(cb, sft);
        int   oi = __shfl_xor(ci, sft);
        minmerge(cb, ci, ov, oi);
      }
      /* thr >= global_screen_min + MARGIN (running-min monotonicity) */
      const float thr = fminf(rv[e], cb) + MARGIN;
      #pragma unroll
      for (int j=0;j<2;j++){
        #pragma unroll
        for (int m=0;m<4;m++){
          const int cl = 128*j + 4*TX + m;
          const float v = __fadd_rn(__fsub_rn(zs, __fmul_rn(2.0f, acc[e*8+j*4+m])),
                                    wsqS[cl]);
          if (v <= thr){
            int slot = atomicAdd(&cntS[row], 1);
            if (slot < CAP) listS[row][slot] = nc*256 + cl;
          }
        }
      }
      minmerge(rv[e], ri[e], cb, ci);
    }
    __syncthreads();
  }

  /* exact-replica rescore: 4 threads/row, candidates strided by 4 */
  {
    const int rr = tid & 63, q = tid >> 6;
    int c = cntS[rr]; if (c > CAP) c = CAP;
    float bv = 3.4e38f; int bi = 0x7fffffff;
    const float zs = zsqS[rr];
    const float* zr = ze + (size_t)(blk*ROWS + rr)*DD;
    for (int i=q; i<c; i+=4){
      const int idx = listS[rr][i];
      const float* wr = W + (size_t)idx*DD;
      float ssum = 0.f;
      for (int k=0;k<256;k++) ssum = __fadd_rn(ssum, __fmul_rn(zr[k], wr[k]));
      const float v = __fadd_rn(__fsub_rn(zs, __fmul_rn(2.0f, ssum)), wsq[idx]);
      minmerge(bv, bi, v, idx);
    }
    rsV[q][rr] = bv; rsI[q][rr] = bi;
  }
  __syncthreads();
  if (tid < ROWS){
    float bv = rsV[0][tid]; int bi = rsI[0][tid];
    #pragma unroll
    for (int q=1;q<4;q++) minmerge(bv, bi, rsV[q][tid], rsI[q][tid]);
    riS[tid] = bi;
  }
  __syncthreads();

  /* epilogue: per row write zq_st, idx; accumulate dist, st, nt */
  float distp = 0.f;
  #pragma unroll
  for (int e=0;e<8;e++){
    const int r    = 8*GRp + e;
    const int grow = blk*ROWS + r;
    const int gi   = riS[r];
    const float* wrow = W + (size_t)gi*DD;
    #pragma unroll
    for (int j=0;j<2;j++){
      const int d = 128*j + 4*TX;
      float4 w4 = *(const float4*)(wrow + d);
      float4 z4 = *(const float4*)&zeS[r*256 + d];
      float4 o;
      o.x = z4.x + (w4.x - z4.x);
      o.y = z4.y + (w4.y - z4.y);
      o.z = z4.z + (w4.z - z4.z);
      o.w = z4.w + (w4.w - z4.w);
      *(float4*)&out[(size_t)grow*DD + d] = o;
      float dx;
      dx = w4.x - z4.x; distp += dx*dx;
      dx = w4.y - z4.y; distp += dx*dx;
      dx = w4.z - z4.z; distp += dx*dx;
      dx = w4.w - z4.w; distp += dx*dx;
      atomicAdd(&st[(size_t)gi*DD + d + 0], z4.x);
      atomicAdd(&st[(size_t)gi*DD + d + 1], z4.y);
      atomicAdd(&st[(size_t)gi*DD + d + 2], z4.z);
      atomicAdd(&st[(size_t)gi*DD + d + 3], z4.w);
    }
    if (TX == 0){
      out[O_IDX + grow] = (float)gi;
      atomicAdd(&nt[gi], 1.0f);
    }
  }
  #pragma unroll
  for (int sft=1; sft<64; sft<<=1) distp += __shfl_xor(distp, sft);
  if ((tid & 63) == 0) atomicAdd(dist_acc, distp);
}

__global__ __launch_bounds__(256,1) void vq_tail_kernel(
    const float* __restrict__ mt, const float* __restrict__ Nt,
    const float* __restrict__ st, const float* __restrict__ nt,
    const float* __restrict__ dist_acc, float* __restrict__ out)
{
  const float G   = 0.99f;
  const float OMG = (float)(1.0 - 0.99);
  const int i = blockIdx.x*256 + threadIdx.x;
  const int k = i >> 8;
  const float ntn = __fadd_rn(__fmul_rn(G, Nt[k]), __fmul_rn(OMG, nt[k]));
  const float mtn = __fadd_rn(__fmul_rn(G, mt[i]), __fmul_rn(OMG, st[i]));
  out[O_MT  + i] = mtn;
  out[O_EMB + i] = mtn / ntn;
  if (i < KC) out[O_NT + i] = __fadd_rn(__fmul_rn(G, Nt[i]), __fmul_rn(OMG, nt[i]));
  if (i == 0) out[O_DIST] = dist_acc[0] * (1.0f/16777216.0f);
}

extern "C" void kernel_launch(void* const* d_in, const int* in_sizes, int n_in,
                              void* d_out, int out_size, void* d_ws, size_t ws_size,
                              hipStream_t stream){
  const float* ze = (const float*)d_in[0];
  const float* W  = (const float*)d_in[1];
  const float* mt = (const float*)d_in[2];
  const float* Nt = (const float*)d_in[3];
  float* out  = (float*)d_out;
  float* ws   = (float*)d_ws;
  float* st   = ws;                 /* KD   */
  float* nt   = ws + KD;            /* KC   */
  float* dist = ws + KD + KC;       /* 1    */
  float* wsq  = ws + KD + KC + 1;   /* KC   */
  float* wtb  = ws + KD + KC + 1 + KC; /* KD: W^T */

  hipMemsetAsync(d_ws, 0, (size_t)(KD + KC + 1)*sizeof(float), stream);
  vq_wsq_kernel <<<KC/256,      256, 0, stream>>>(W, wsq);
  vq_wt_kernel  <<<dim3(16,4),  256, 0, stream>>>(W, wtb);
  vq_main_kernel<<<NROWS/ROWS,  256, 0, stream>>>(ze, W, wtb, wsq, out, st, nt, dist);
  vq_tail_kernel<<<KD/256,      256, 0, stream>>>(mt, Nt, st, nt, dist, out);
}

// Round 8
// 637.126 us; speedup vs baseline: 3.1021x; 1.4058x over previous
//
#include <hip/hip_runtime.h>

#define NROWS 65536
#define KC    1024
#define DD    256
#define ND    (NROWS*DD)      /* 16777216 */
#define KD    (KC*DD)         /* 262144 */
#define BROWS 128             /* rows per main block */
#define CAP   32              /* candidate list capacity per row */
#define MARGIN 2.0f           /* >=2E for bf16-screen vs exact-replica (~8 sigma) */

/* output offsets (floats), concatenated in reference return order */
#define O_ZQ   0
#define O_DIST ND
#define O_IDX  (ND+1)
#define O_EMB  (ND+1+NROWS)
#define O_MT   (O_EMB+KD)
#define O_NT   (O_MT+KD)

/* ws float offsets */
#define WS_ST   0
#define WS_NT   KD
#define WS_DIST (KD+KC)
#define WS_WSQ  (KD+KC+1)
#define WS_WPK  (KD+2*KC+4)   /* 16B-aligned; 512KB of bf16 W fragments */

typedef __attribute__((ext_vector_type(8))) short bf16x8;
typedef __attribute__((ext_vector_type(4))) float f32x4;

/* ===== exact-replica arithmetic contract (validated rounds 5-7) =====
   ref dist d2[r][c] = fadd( fsub( zsq[r], fmul(2, dot) ), wsq[c] )
   dot  = sequential ascending-k, SEPARATE mul+add roundings, single acc
   zsq/wsq = strict sequential sum of squares (mul+add, ascending)
   argmin  = first occurrence of min.
   Screen = bf16 MFMA GEMM; every code within MARGIN of its (pass,colgroup)
   screen-min is rescored with the exact replica chain. Proof: for true
   argmin c*, any code beating it by >MARGIN on screen would beat it
   exactly (MARGIN >= 2E), contradiction -> c* is always collected. */

static __device__ __forceinline__ void minmerge(float& bv, int& bi, float ov, int oi){
  if (ov < bv || (ov == bv && oi < bi)) { bv = ov; bi = oi; }
}

static __device__ __forceinline__ float seq_sumsq_256(const float* __restrict__ x){
  float s = __fmul_rn(x[0], x[0]);
  for (int i=1;i<256;i++) s = __fadd_rn(s, __fmul_rn(x[i], x[i]));
  return s;
}

static __device__ __forceinline__ unsigned short f2bf(float f){
  unsigned u = __float_as_uint(f);
  unsigned r = (u + 0x7FFFu + ((u>>16)&1u)) >> 16;   /* RNE */
  return (unsigned short)r;
}
static __device__ __forceinline__ bf16x8 cvt8(float4 a, float4 b){
  bf16x8 v;
  v[0]=(short)f2bf(a.x); v[1]=(short)f2bf(a.y); v[2]=(short)f2bf(a.z); v[3]=(short)f2bf(a.w);
  v[4]=(short)f2bf(b.x); v[5]=(short)f2bf(b.y); v[6]=(short)f2bf(b.z); v[7]=(short)f2bf(b.w);
  return v;
}

__global__ __launch_bounds__(256,1) void vq_wsq_kernel(const float* __restrict__ W,
                                                       float* __restrict__ wsq){
  const int k = blockIdx.x*256 + threadIdx.x;
  wsq[k] = seq_sumsq_256(W + (size_t)k*DD);
}

/* W [1024][256] f32 -> bf16 fragments in MFMA-B order:
   frag index = ((ct*8 + s)*64 + lane), lane = (c&15) + 16*lg,
   ct = c>>4, s = k0>>5, lg = (k0>>3)&3  (k0 = 8-aligned k base). */
__global__ __launch_bounds__(256,1) void vq_wpack_kernel(const float* __restrict__ W,
                                                         bf16x8* __restrict__ wpk){
  const int g = blockIdx.x*256 + threadIdx.x;   /* 0..32767 */
  const int c  = g >> 5;
  const int kb = g & 31;                        /* k-block of 8 */
  float4 a = *(const float4*)&W[(size_t)c*DD + kb*8];
  float4 b = *(const float4*)&W[(size_t)c*DD + kb*8 + 4];
  wpk[((c>>4)*8 + (kb>>2))*64 + (c&15) + 16*(kb&3)] = cvt8(a,b);
}

/* Main: 512 thr = 8 waves (2 row-groups x 4 col-groups).
   Block tile 128 rows x 1024 codes. Per wave: 64 rows x 256 cols in
   2 passes of 128 cols; per pass m=4 x n=8 tiles of 16x16, K=256 in 8
   slices of 32 via v_mfma_f32_16x16x32_bf16.
   A frags from LDS (linear pack, conflict-free); B frags from global wpk
   (coalesced dwordx4, L2-resident 512KB). */
__global__ __launch_bounds__(512,2) void vq_main_kernel(
    const float* __restrict__ ze, const float* __restrict__ W,
    const bf16x8* __restrict__ wpk, const float* __restrict__ wsq,
    float* __restrict__ out, float* __restrict__ st, float* __restrict__ nt,
    float* __restrict__ dist_acc)
{
  __shared__ bf16x8 apkS[4096];        /* 64 KB: A fragments, linear */
  __shared__ float  wsqS[KC];          /* 4 KB */
  __shared__ float  zsqS[BROWS];
  __shared__ int    cntS[BROWS];
  __shared__ int    listS[BROWS][CAP]; /* 16 KB */
  __shared__ int    riS[BROWS];
  __shared__ float  rsV[4][BROWS];
  __shared__ int    rsI[4][BROWS];

  const int tid = threadIdx.x;
  const int blk = blockIdx.x;
  const float* zb = ze + (size_t)blk*BROWS*DD;

  /* ---- phase 1: convert z tile to A fragments + init ---- */
  #pragma unroll
  for (int it=0; it<8; ++it){
    const int g  = it*512 + tid;       /* 0..4095 */
    const int r  = g >> 5;             /* row 0..127 */
    const int kb = g & 31;             /* k-block of 8 */
    float4 a = *(const float4*)&zb[(size_t)r*DD + kb*8];
    float4 b = *(const float4*)&zb[(size_t)r*DD + kb*8 + 4];
    apkS[((r>>4)*8 + (kb>>2))*64 + (r&15) + 16*(kb&3)] = cvt8(a,b);
  }
  wsqS[tid]     = wsq[tid];
  wsqS[tid+512] = wsq[tid+512];
  if (tid < BROWS){
    cntS[tid] = 0;
    zsqS[tid] = seq_sumsq_256(zb + (size_t)tid*DD);   /* exact replica */
  }
  __syncthreads();

  /* ---- phase 2: MFMA screen + candidate collection ---- */
  const int lane = tid & 63;
  const int wv   = tid >> 6;       /* 0..7 */
  const int rg   = wv >> 2;        /* 0..1 : 64-row group */
  const int cg   = wv & 3;         /* 0..3 : 256-col group */

  #pragma unroll
  for (int p=0; p<2; ++p){
    f32x4 acc[4][8];
    #pragma unroll
    for (int mt=0; mt<4; ++mt)
      #pragma unroll
      for (int nt=0; nt<8; ++nt)
        acc[mt][nt] = (f32x4){0.f,0.f,0.f,0.f};

    #pragma unroll
    for (int s=0; s<8; ++s){
      bf16x8 af[4], bf[8];
      #pragma unroll
      for (int mt=0; mt<4; ++mt)
        af[mt] = apkS[((rg*4+mt)*8 + s)*64 + lane];
      #pragma unroll
      for (int nt=0; nt<8; ++nt)
        bf[nt] = wpk[(size_t)(((cg*16 + p*8 + nt)*8 + s)*64 + lane)];
      #pragma unroll
      for (int mt=0; mt<4; ++mt)
        #pragma unroll
        for (int nt=0; nt<8; ++nt)
          acc[mt][nt] = __builtin_amdgcn_mfma_f32_16x16x32_bf16(af[mt], bf[nt], acc[mt][nt], 0,0,0);
    }

    /* screen: per (mt, reg r) this lane owns row rg*64+mt*16+(lane>>4)*4+r,
       cols (cg*16+p*8+nt)*16 + (lane&15). Collect all within MARGIN of the
       per-(pass,colgroup) row min. */
    #pragma unroll
    for (int mt=0; mt<4; ++mt){
      #pragma unroll
      for (int r=0; r<4; ++r){
        const int row = rg*64 + mt*16 + (lane>>4)*4 + r;
        const float zs = zsqS[row];
        float dv[8]; float mn = 3.4e38f;
        #pragma unroll
        for (int nt=0; nt<8; ++nt){
          const int col = (cg*16 + p*8 + nt)*16 + (lane&15);
          dv[nt] = __fadd_rn(__fsub_rn(zs, __fmul_rn(2.0f, acc[mt][nt][r])), wsqS[col]);
          mn = fminf(mn, dv[nt]);
        }
        #pragma unroll
        for (int m=1; m<16; m<<=1) mn = fminf(mn, __shfl_xor(mn, m));
        const float thr = mn + MARGIN;
        #pragma unroll
        for (int nt=0; nt<8; ++nt){
          if (dv[nt] <= thr){
            int slot = atomicAdd(&cntS[row], 1);
            if (slot < CAP) listS[row][slot] = (cg*16 + p*8 + nt)*16 + (lane&15);
          }
        }
      }
    }
  }
  __syncthreads();

  /* ---- phase 3: exact-replica rescore (4 threads/row) ---- */
  {
    const int q  = tid >> 7;       /* 0..3 */
    const int rr = tid & 127;
    int c = cntS[rr]; if (c > CAP) c = CAP;
    float bv = 3.4e38f; int bi = 0x7fffffff;
    const float zs = zsqS[rr];
    const float* zr = zb + (size_t)rr*DD;
    for (int i=q; i<c; i+=4){
      const int idx = listS[rr][i];
      const float* wr = W + (size_t)idx*DD;
      float ssum = 0.f;
      for (int k=0;k<256;k++) ssum = __fadd_rn(ssum, __fmul_rn(zr[k], wr[k]));
      const float v = __fadd_rn(__fsub_rn(zs, __fmul_rn(2.0f, ssum)), wsqS[idx]);
      minmerge(bv, bi, v, idx);
    }
    rsV[q][rr] = bv; rsI[q][rr] = bi;
  }
  __syncthreads();
  if (tid < BROWS){
    float bv = rsV[0][tid]; int bi = rsI[0][tid];
    #pragma unroll
    for (int q=1;q<4;q++) minmerge(bv, bi, rsV[q][tid], rsI[q][tid]);
    riS[tid] = bi;
  }
  __syncthreads();

  /* ---- phase 4: epilogue (zq_st, idx, dist, st, nt) ---- */
  float distp = 0.f;
  const int GRp = tid >> 5;   /* 0..15 */
  const int TX  = tid & 31;
  #pragma unroll
  for (int e=0; e<8; ++e){
    const int r    = GRp*8 + e;
    const int grow = blk*BROWS + r;
    const int gi   = riS[r];
    const float* wrow = W + (size_t)gi*DD;
    const float* zrow = zb + (size_t)r*DD;
    #pragma unroll
    for (int j=0;j<2;j++){
      const int d = 128*j + 4*TX;
      float4 w4 = *(const float4*)(wrow + d);
      float4 z4 = *(const float4*)(zrow + d);
      float4 o;
      o.x = z4.x + (w4.x - z4.x);
      o.y = z4.y + (w4.y - z4.y);
      o.z = z4.z + (w4.z - z4.z);
      o.w = z4.w + (w4.w - z4.w);
      *(float4*)&out[(size_t)grow*DD + d] = o;
      float dx;
      dx = w4.x - z4.x; distp += dx*dx;
      dx = w4.y - z4.y; distp += dx*dx;
      dx = w4.z - z4.z; distp += dx*dx;
      dx = w4.w - z4.w; distp += dx*dx;
      atomicAdd(&st[(size_t)gi*DD + d + 0], z4.x);
      atomicAdd(&st[(size_t)gi*DD + d + 1], z4.y);
      atomicAdd(&st[(size_t)gi*DD + d + 2], z4.z);
      atomicAdd(&st[(size_t)gi*DD + d + 3], z4.w);
    }
    if (TX == 0){
      out[O_IDX + grow] = (float)gi;
      atomicAdd(&nt[gi], 1.0f);
    }
  }
  #pragma unroll
  for (int m=1; m<64; m<<=1) distp += __shfl_xor(distp, m);
  if ((tid & 63) == 0) atomicAdd(dist_acc, distp);
}

__global__ __launch_bounds__(256,1) void vq_tail_kernel(
    const float* __restrict__ mt, const float* __restrict__ Nt,
    const float* __restrict__ st, const float* __restrict__ nt,
    const float* __restrict__ dist_acc, float* __restrict__ out)
{
  const float G   = 0.99f;
  const float OMG = (float)(1.0 - 0.99);
  const int i = blockIdx.x*256 + threadIdx.x;
  const int k = i >> 8;
  const float ntn = __fadd_rn(__fmul_rn(G, Nt[k]), __fmul_rn(OMG, nt[k]));
  const float mtn = __fadd_rn(__fmul_rn(G, mt[i]), __fmul_rn(OMG, st[i]));
  out[O_MT  + i] = mtn;
  out[O_EMB + i] = mtn / ntn;
  if (i < KC) out[O_NT + i] = __fadd_rn(__fmul_rn(G, Nt[i]), __fmul_rn(OMG, nt[i]));
  if (i == 0) out[O_DIST] = dist_acc[0] * (1.0f/16777216.0f);
}

extern "C" void kernel_launch(void* const* d_in, const int* in_sizes, int n_in,
                              void* d_out, int out_size, void* d_ws, size_t ws_size,
                              hipStream_t stream){
  const float* ze = (const float*)d_in[0];
  const float* W  = (const float*)d_in[1];
  const float* mt = (const float*)d_in[2];
  const float* Nt = (const float*)d_in[3];
  float* out  = (float*)d_out;
  float* ws   = (float*)d_ws;
  float*  st_  = ws + WS_ST;
  float*  nt_  = ws + WS_NT;
  float*  dist = ws + WS_DIST;
  float*  wsq  = ws + WS_WSQ;
  bf16x8* wpk  = (bf16x8*)(ws + WS_WPK);

  hipMemsetAsync(d_ws, 0, (size_t)(KD + KC + 1)*sizeof(float), stream);
  vq_wsq_kernel  <<<KC/256,      256, 0, stream>>>(W, wsq);
  vq_wpack_kernel<<<128,         256, 0, stream>>>(W, wpk);
  vq_main_kernel <<<NROWS/BROWS, 512, 0, stream>>>(ze, W, wpk, wsq, out, st_, nt_, dist);
  vq_tail_kernel <<<KD/256,      256, 0, stream>>>(mt, Nt, st_, nt_, dist, out);
}